// Round 5
// baseline (405.219 us; speedup 1.0000x reference)
//
#include <hip/hip_runtime.h>
#include <hip/hip_bf16.h>

typedef __attribute__((ext_vector_type(8))) short bf16x8;
typedef __attribute__((ext_vector_type(4))) float f32x4;

// round-to-nearest-even float -> bf16 bits
static __device__ __forceinline__ short f2bf(float x) {
    union { float f; unsigned u; } v; v.f = x;
    unsigned r = v.u + 0x7FFFu + ((v.u >> 16) & 1u);
    return (short)(r >> 16);
}

// packed RNE f32x2 -> bf16x2 (hardware)
static __device__ __forceinline__ unsigned cvt_pk_bf16(float lo, float hi) {
    unsigned r;
    asm("v_cvt_pk_bf16_f32 %0, %1, %2" : "=v"(r) : "v"(lo), "v"(hi));
    return r;
}

// W1 [K=256][N=256] fp32 -> W1T [N=256][K=256] bf16
__global__ void prep_w1t(const float* __restrict__ W1, short* __restrict__ W1T) {
    int t = blockIdx.x * 256 + threadIdx.x;
    int n = t >> 8, k = t & 255;
    W1T[t] = f2bf(W1[k * 256 + n]);
}

// Bank swizzle: maps the 4 simultaneous conv-writer rows (low-2 bits) AND the
// 16 MFMA-reader rows (low-4 bits, via c) onto distinct bank-group XORs.
// Write-side and read-side both resolve to 2-way (free) conflicts.
#define SWZ8(r) ((((r) & 3) << 1) | (((r) >> 2) & 1))

// One block = one 64-row tile. 256 threads = 4 waves, 4 col-passes of 64.
// Swapped-operand MFMA: D's (g,reg) dim = W1 col, lane&15 dim = pair row.
__global__ __launch_bounds__(256, 4)
void pair_mlp(const int* __restrict__ pidx, const int* __restrict__ qidx,
              const float* __restrict__ emb, const short* __restrict__ w1t,
              const float* __restrict__ b1, const float* __restrict__ w2,
              const float* __restrict__ b2p, float* __restrict__ out, int M)
{
    __shared__ short At[64 * 256];   // 32 KB bf16 A-tile (full K)
    __shared__ float Red[4 * 64];    // 1 KB cross-wave reduction

    const int tid  = threadIdx.x;
    const int lane = tid & 63;
    const int wv   = tid >> 6;       // wave 0..3
    const int c    = lane & 15;
    const int g    = lane >> 4;
    const int base = blockIdx.x * 64;

    // ---- conv phase: gather rows, diff^2 -> bf16 -> LDS ----
    {
        const int r  = tid >> 2;     // tile row 0..63
        const int sg = tid & 3;      // 8-float segment within K=32
        int im = base + r; im = im < M ? im : M - 1;
        const float* pp = emb + (size_t)pidx[im] * 256;
        const float* qp = emb + (size_t)qidx[im] * 256;
        const int sw = SWZ8(r);
        short* rowp = At + r * 256;
#pragma unroll 2
        for (int s = 0; s < 8; ++s) {
            const float* ps = pp + s * 32 + sg * 8;
            const float* qs = qp + s * 32 + sg * 8;
            float4 P0 = ((const float4*)ps)[0], P1 = ((const float4*)ps)[1];
            float4 Q0 = ((const float4*)qs)[0], Q1 = ((const float4*)qs)[1];
            float d0 = P0.x - Q0.x, d1 = P0.y - Q0.y;
            float d2 = P0.z - Q0.z, d3 = P0.w - Q0.w;
            float d4 = P1.x - Q1.x, d5 = P1.y - Q1.y;
            float d6 = P1.z - Q1.z, d7 = P1.w - Q1.w;
            union { bf16x8 v; unsigned u[4]; } a;
            a.u[0] = cvt_pk_bf16(d0 * d0, d1 * d1);
            a.u[1] = cvt_pk_bf16(d2 * d2, d3 * d3);
            a.u[2] = cvt_pk_bf16(d4 * d4, d5 * d5);
            a.u[3] = cvt_pk_bf16(d6 * d6, d7 * d7);
            int slot = (s * 4 + sg) ^ sw;
            *(bf16x8*)(rowp + slot * 8) = a.v;
        }
    }
    __syncthreads();

    // ---- 4 col-passes of MFMA + relu-dot epilogue ----
    float part[4] = {0.f, 0.f, 0.f, 0.f};

#pragma unroll 1
    for (int pass = 0; pass < 4; ++pass) {
        const int colbase = pass * 64 + wv * 16;

        bf16x8 bfr[8];
#pragma unroll
        for (int kc = 0; kc < 8; ++kc)
            bfr[kc] = *(const bf16x8*)(w1t + (colbase + c) * 256 + kc * 32 + g * 8);

        float b1v[4], w2v[4];
#pragma unroll
        for (int j = 0; j < 4; ++j) {
            b1v[j] = b1[colbase + g * 4 + j];
            w2v[j] = w2[colbase + g * 4 + j];
        }

        f32x4 acc[4];
#pragma unroll
        for (int m = 0; m < 4; ++m) acc[m] = (f32x4)0.0f;

#pragma unroll
        for (int kc = 0; kc < 8; ++kc) {
#pragma unroll
            for (int m = 0; m < 4; ++m) {
                const int row = m * 16 + c;
                const int slot = (kc * 4 + g) ^ SWZ8(row);
                bf16x8 a = *(const bf16x8*)(At + row * 256 + slot * 8);
                acc[m] = __builtin_amdgcn_mfma_f32_16x16x32_bf16(
                    bfr[kc], a, acc[m], 0, 0, 0);
            }
        }

        // lane(c,g) reg j holds h[row m*16+c][col colbase + g*4 + j]
#pragma unroll
        for (int m = 0; m < 4; ++m)
#pragma unroll
            for (int j = 0; j < 4; ++j) {
                float h = acc[m][j] + b1v[j];
                h = h > 0.f ? h : 0.f;
                part[m] += h * w2v[j];
            }
    }

    // reduce over g (lanes 16/32 apart); g==0 lanes hold per-row sums
#pragma unroll
    for (int m = 0; m < 4; ++m) {
        part[m] += __shfl_xor(part[m], 16, 64);
        part[m] += __shfl_xor(part[m], 32, 64);
    }
    if (g == 0) {
#pragma unroll
        for (int m = 0; m < 4; ++m) Red[wv * 64 + m * 16 + c] = part[m];
    }
    __syncthreads();

    if (tid < 64) {
        int row = base + tid;
        if (row < M) {
            float s = b2p[0] + Red[tid] + Red[64 + tid] +
                      Red[128 + tid] + Red[192 + tid];
            out[row] = s;
        }
    }
}

extern "C" void kernel_launch(void* const* d_in, const int* in_sizes, int n_in,
                              void* d_out, int out_size, void* d_ws, size_t ws_size,
                              hipStream_t stream) {
    const int*   p   = (const int*)d_in[0];
    const int*   q   = (const int*)d_in[1];
    const float* emb = (const float*)d_in[2];
    const float* W1  = (const float*)d_in[3];
    const float* b1  = (const float*)d_in[4];
    const float* W2  = (const float*)d_in[5];
    const float* b2  = (const float*)d_in[6];
    float* out = (float*)d_out;
    short* w1t = (short*)d_ws;          // 128 KB scratch
    int M = in_sizes[0];
    int NT = (M + 63) / 64;

    prep_w1t<<<256, 256, 0, stream>>>(W1, w1t);
    pair_mlp<<<NT, 256, 0, stream>>>(p, q, emb, w1t, b1, W2, b2, out, M);
}

// Round 6
// 158.429 us; speedup vs baseline: 2.5577x; 2.5577x over previous
//
#include <hip/hip_runtime.h>
#include <hip/hip_bf16.h>

typedef __attribute__((ext_vector_type(8))) short bf16x8;
typedef __attribute__((ext_vector_type(4))) float f32x4;

// round-to-nearest-even float -> bf16 bits
static __device__ __forceinline__ short f2bf(float x) {
    union { float f; unsigned u; } v; v.f = x;
    unsigned r = v.u + 0x7FFFu + ((v.u >> 16) & 1u);
    return (short)(r >> 16);
}

// packed RNE f32x2 -> bf16x2 (hardware)
static __device__ __forceinline__ unsigned cvt_pk_bf16(float lo, float hi) {
    unsigned r;
    asm("v_cvt_pk_bf16_f32 %0, %1, %2" : "=v"(r) : "v"(lo), "v"(hi));
    return r;
}

// W1 [K=256][N=256] fp32 -> W1T [N=256][K=256] bf16
__global__ void prep_w1t(const float* __restrict__ W1, short* __restrict__ W1T) {
    int t = blockIdx.x * 256 + threadIdx.x;
    int n = t >> 8, k = t & 255;
    W1T[t] = f2bf(W1[k * 256 + n]);
}

#define NBLK 256

// Persistent kernel: 256 blocks x 1024 threads (16 waves, 4/SIMD).
// LDS: full W1T (128 KB, swizzled) + double-buffered A K=64 slices (2x16 KB)
//      = 160 KiB; epilogue Red aliases Abuf[1].
// Wave w: col-group cg=w&7 (32 cols as n=0,1), row-half rh=w>>3 (64 rows as
// m=0..3). Swapped-operand MFMA: D (g,reg)=col-in-16, lane&15=pair-row.
// XOR swizzle slot = kgran ^ (row&7) on both A and B: conflict-free writes
// (each writer row covers all 8 granules) and reads ((kk*4+g)^(c&7) uniform).
__global__ __launch_bounds__(1024)
void pair_mlp(const int* __restrict__ pidx, const int* __restrict__ qidx,
              const float* __restrict__ emb, const short* __restrict__ w1t,
              const float* __restrict__ b1, const float* __restrict__ w2,
              const float* __restrict__ b2p, float* __restrict__ out,
              int M, int NT)
{
    __shared__ short Blds[256 * 256];     // 128 KB: [col][kgran ^ (col&7)]
    __shared__ short Abuf[2][128 * 64];   // 2 x 16 KB K-slices
    float* Red = (float*)&Abuf[1][0];     // 4 KB, aliased (dead at epilogue)

    const int tid  = threadIdx.x;
    const int lane = tid & 63;
    const int wv   = tid >> 6;     // 0..15
    const int c    = lane & 15;
    const int g    = lane >> 4;
    const int cg   = wv & 7;       // col-group (32 cols)
    const int rh   = wv >> 3;      // row-half (64 rows)

    // ---- stage W1T -> LDS once (coalesced 16B loads, XOR-swizzled store) ----
#pragma unroll
    for (int it = 0; it < 8; ++it) {
        int G = it * 1024 + tid;               // granule id 0..8191
        int col = G >> 5, kg = G & 31;
        bf16x8 v = *(const bf16x8*)(w1t + G * 8);
        *(bf16x8*)(Blds + (col * 32 + (kg ^ (col & 7))) * 8) = v;
    }

    // persistent epilogue constants: cols cg*32 + n*16 + g*4 + j
    float b1v[2][4], w2v[2][4];
#pragma unroll
    for (int n = 0; n < 2; ++n)
#pragma unroll
        for (int j = 0; j < 4; ++j) {
            b1v[n][j] = b1[cg * 32 + n * 16 + g * 4 + j];
            w2v[n][j] = w2[cg * 32 + n * 16 + g * 4 + j];
        }
    const float b2v = b2p[0];
    __syncthreads();

    const int r  = tid >> 3;       // gather row 0..127
    const int sg = tid & 7;        // K-granule within 64-K slice
    const int wslot = (sg ^ (r & 7)) * 8;

    // prefetched pair indices for the first tile
    int im0 = blockIdx.x * 128 + r; im0 = im0 < M ? im0 : M - 1;
    int pi = pidx[im0], qi = qidx[im0];

#define LOADW(W, S)                                                      \
    {                                                                    \
        const float* ps = pp + (S) * 64;                                 \
        const float* qs = qp + (S) * 64;                                 \
        P0_##W = ((const float4*)ps)[0]; P1_##W = ((const float4*)ps)[1];\
        Q0_##W = ((const float4*)qs)[0]; Q1_##W = ((const float4*)qs)[1];\
    }

#define CONV(W, BUF)                                                     \
    {                                                                    \
        float d0 = P0_##W.x - Q0_##W.x, d1 = P0_##W.y - Q0_##W.y;        \
        float d2 = P0_##W.z - Q0_##W.z, d3 = P0_##W.w - Q0_##W.w;        \
        float d4 = P1_##W.x - Q1_##W.x, d5 = P1_##W.y - Q1_##W.y;        \
        float d6 = P1_##W.z - Q1_##W.z, d7 = P1_##W.w - Q1_##W.w;        \
        union { bf16x8 v; unsigned u[4]; } a;                            \
        a.u[0] = cvt_pk_bf16(d0 * d0, d1 * d1);                          \
        a.u[1] = cvt_pk_bf16(d2 * d2, d3 * d3);                          \
        a.u[2] = cvt_pk_bf16(d4 * d4, d5 * d5);                          \
        a.u[3] = cvt_pk_bf16(d6 * d6, d7 * d7);                          \
        *(bf16x8*)(&Abuf[BUF][0] + r * 64 + wslot) = a.v;                \
    }

#define MFMA_STEP(S, BUF)                                                \
    {                                                                    \
        const short* ab = &Abuf[BUF][0];                                 \
        _Pragma("unroll")                                                \
        for (int kk = 0; kk < 2; ++kk) {                                 \
            int bs = ((S) * 8 + kk * 4 + g) ^ (c & 7);                   \
            bf16x8 bf0 = *(const bf16x8*)(Blds + ((cg * 32 + c) * 32 + bs) * 8);      \
            bf16x8 bf1 = *(const bf16x8*)(Blds + ((cg * 32 + 16 + c) * 32 + bs) * 8); \
            _Pragma("unroll")                                            \
            for (int m = 0; m < 4; ++m) {                                \
                int row = rh * 64 + m * 16 + c;                          \
                bf16x8 af = *(const bf16x8*)(ab + row * 64 +             \
                                             (((kk * 4 + g) ^ (c & 7)) * 8)); \
                acc[m][0] = __builtin_amdgcn_mfma_f32_16x16x32_bf16(     \
                    bf0, af, acc[m][0], 0, 0, 0);                        \
                acc[m][1] = __builtin_amdgcn_mfma_f32_16x16x32_bf16(     \
                    bf1, af, acc[m][1], 0, 0, 0);                        \
            }                                                            \
        }                                                                \
    }

    for (int tile = blockIdx.x; tile < NT; tile += NBLK) {
        const int base = tile * 128;
        const float* pp = emb + (size_t)pi * 256 + sg * 8;
        const float* qp = emb + (size_t)qi * 256 + sg * 8;

        float4 P0_0, P1_0, Q0_0, Q1_0, P0_1, P1_1, Q0_1, Q1_1;
        LOADW(0, 0)
        LOADW(1, 1)

        // prefetch next tile's indices (latency hidden under this tile)
        int pi_n = pi, qi_n = qi;
        {
            int t2 = tile + NBLK;
            if (t2 < NT) {
                int im2 = t2 * 128 + r; im2 = im2 < M ? im2 : M - 1;
                pi_n = pidx[im2]; qi_n = qidx[im2];
            }
        }

        CONV(0, 0)

        f32x4 acc[4][2];
#pragma unroll
        for (int m = 0; m < 4; ++m) { acc[m][0] = (f32x4)0.0f; acc[m][1] = (f32x4)0.0f; }

        // s = 0
        __syncthreads();
        LOADW(0, 2)
        MFMA_STEP(0, 0)
        CONV(1, 1)
        // s = 1
        __syncthreads();
        LOADW(1, 3)
        MFMA_STEP(1, 1)
        CONV(0, 0)
        // s = 2
        __syncthreads();
        MFMA_STEP(2, 0)
        CONV(1, 1)
        // s = 3
        __syncthreads();
        MFMA_STEP(3, 1)

        // ---- epilogue ----
        float part[4];
#pragma unroll
        for (int m = 0; m < 4; ++m) {
            float s = 0.f;
#pragma unroll
            for (int n = 0; n < 2; ++n)
#pragma unroll
                for (int j = 0; j < 4; ++j) {
                    float h = acc[m][n][j] + b1v[n][j];
                    h = h > 0.f ? h : 0.f;
                    s += h * w2v[n][j];
                }
            part[m] = s;
        }
#pragma unroll
        for (int m = 0; m < 4; ++m) {
            part[m] += __shfl_xor(part[m], 16, 64);
            part[m] += __shfl_xor(part[m], 32, 64);
        }

        __syncthreads();            // all buf1 MFMA reads done (Red aliases it)
        if (g == 0) {
#pragma unroll
            for (int m = 0; m < 4; ++m)
                Red[cg * 128 + rh * 64 + m * 16 + c] = part[m];
        }
        __syncthreads();
        if (tid < 128) {
            int row = base + tid;
            if (row < M) {
                float s = b2v;
#pragma unroll
                for (int k = 0; k < 8; ++k) s += Red[k * 128 + tid];
                out[row] = s;
            }
        }
        pi = pi_n; qi = qi_n;
        // next iteration: prologue CONV writes buf0 (disjoint from Red/buf1);
        // the s=0 barrier orders Red reads before buf1's next conv write.
    }
#undef LOADW
#undef CONV
#undef MFMA_STEP
}

extern "C" void kernel_launch(void* const* d_in, const int* in_sizes, int n_in,
                              void* d_out, int out_size, void* d_ws, size_t ws_size,
                              hipStream_t stream) {
    const int*   p   = (const int*)d_in[0];
    const int*   q   = (const int*)d_in[1];
    const float* emb = (const float*)d_in[2];
    const float* W1  = (const float*)d_in[3];
    const float* b1  = (const float*)d_in[4];
    const float* W2  = (const float*)d_in[5];
    const float* b2  = (const float*)d_in[6];
    float* out = (float*)d_out;
    short* w1t = (short*)d_ws;          // 128 KB scratch
    int M = in_sizes[0];
    int NT = (M + 127) / 128;

    prep_w1t<<<256, 256, 0, stream>>>(W1, w1t);
    pair_mlp<<<NBLK, 1024, 0, stream>>>(p, q, emb, w1t, b1, W2, b2, out, M, NT);
}

// Round 7
// 111.420 us; speedup vs baseline: 3.6368x; 1.4219x over previous
//
#include <hip/hip_runtime.h>
#include <hip/hip_bf16.h>

typedef __attribute__((ext_vector_type(8))) short bf16x8;
typedef __attribute__((ext_vector_type(4))) float f32x4;
typedef _Float16 h16x8 __attribute__((ext_vector_type(8)));

// round-to-nearest-even float -> bf16 bits
static __device__ __forceinline__ short f2bf(float x) {
    union { float f; unsigned u; } v; v.f = x;
    unsigned r = v.u + 0x7FFFu + ((v.u >> 16) & 1u);
    return (short)(r >> 16);
}

// packed RNE f32x2 -> bf16x2 (hardware)
static __device__ __forceinline__ unsigned cvt_pk_bf16(float lo, float hi) {
    unsigned r;
    asm("v_cvt_pk_bf16_f32 %0, %1, %2" : "=v"(r) : "v"(lo), "v"(hi));
    return r;
}

// W1 [K=256][N=256] fp32 -> W1T [N=256][K=256] bf16
__global__ void prep_w1t(const float* __restrict__ W1, short* __restrict__ W1T) {
    int t = blockIdx.x * 256 + threadIdx.x;
    int n = t >> 8, k = t & 255;
    W1T[t] = f2bf(W1[k * 256 + n]);
}

// embedding f32 -> f16 (halves gather bytes; fp16 rel-err 2^-11 is 4x finer
// than bf16, keeps total error well under threshold)
__global__ void prep_emb16(const float* __restrict__ src, _Float16* __restrict__ dst,
                           int n8) {
    int t = blockIdx.x * 256 + threadIdx.x;
    if (t >= n8) return;
    const float4 a = ((const float4*)src)[t * 2];
    const float4 b = ((const float4*)src)[t * 2 + 1];
    h16x8 h;
    h[0] = (_Float16)a.x; h[1] = (_Float16)a.y;
    h[2] = (_Float16)a.z; h[3] = (_Float16)a.w;
    h[4] = (_Float16)b.x; h[5] = (_Float16)b.y;
    h[6] = (_Float16)b.z; h[7] = (_Float16)b.w;
    *(h16x8*)(dst + t * 8) = h;
}

#define NBLK 256

// Persistent kernel: 256 blocks x 1024 threads (16 waves, 4/SIMD).
// LDS: full W1T (128 KB, XOR-swizzled) + double-buffered A K=64 slices
// (2 x 16 KB) = 160 KiB; epilogue Red aliases Abuf[1].
// fp16 embedding gathers; 4 rotating load-windows with ~2-phase issue
// distance, prefetching ACROSS tile boundaries (no tile-start stall).
__global__ __launch_bounds__(1024)
void pair_mlp_f16(const int* __restrict__ pidx, const int* __restrict__ qidx,
                  const _Float16* __restrict__ emb, const short* __restrict__ w1t,
                  const float* __restrict__ b1, const float* __restrict__ w2,
                  const float* __restrict__ b2p, float* __restrict__ out,
                  int M, int NT)
{
    __shared__ short Blds[256 * 256];     // 128 KB: [col][kgran ^ (col&7)]
    __shared__ short Abuf[2][128 * 64];   // 2 x 16 KB K-slices
    float* Red = (float*)&Abuf[1][0];     // 4 KB, aliased (dead at epilogue)

    const int tid  = threadIdx.x;
    const int lane = tid & 63;
    const int wv   = tid >> 6;     // 0..15
    const int c    = lane & 15;
    const int g    = lane >> 4;
    const int cg   = wv & 7;       // col-group (32 cols)
    const int rh   = wv >> 3;      // row-half (64 rows)

    // ---- stage W1T -> LDS once ----
#pragma unroll
    for (int it = 0; it < 8; ++it) {
        int G = it * 1024 + tid;
        int col = G >> 5, kg = G & 31;
        bf16x8 v = *(const bf16x8*)(w1t + G * 8);
        *(bf16x8*)(Blds + (col * 32 + (kg ^ (col & 7))) * 8) = v;
    }

    float b1v[2][4], w2v[2][4];
#pragma unroll
    for (int n = 0; n < 2; ++n)
#pragma unroll
        for (int j = 0; j < 4; ++j) {
            b1v[n][j] = b1[cg * 32 + n * 16 + g * 4 + j];
            w2v[n][j] = w2[cg * 32 + n * 16 + g * 4 + j];
        }
    const float b2v = b2p[0];
    __syncthreads();

    const int r  = tid >> 3;       // gather row 0..127
    const int sg = tid & 7;        // 8-elem K-granule within 64-K slice
    const int wslot = (sg ^ (r & 7)) * 8;

    int im0 = blockIdx.x * 128 + r; im0 = im0 < M ? im0 : M - 1;
    int pi = pidx[im0], qi = qidx[im0];

    h16x8 wp[4], wq[4];            // 4 rotating windows (4 VGPR each half)

#define LD(W, PP, QP, S)                                                 \
    {                                                                    \
        wp[W] = *(const h16x8*)((PP) + (S) * 64);                        \
        wq[W] = *(const h16x8*)((QP) + (S) * 64);                        \
    }

#define CONV(W, BUF)                                                     \
    {                                                                    \
        float d0 = (float)wp[W][0] - (float)wq[W][0];                    \
        float d1 = (float)wp[W][1] - (float)wq[W][1];                    \
        float d2 = (float)wp[W][2] - (float)wq[W][2];                    \
        float d3 = (float)wp[W][3] - (float)wq[W][3];                    \
        float d4 = (float)wp[W][4] - (float)wq[W][4];                    \
        float d5 = (float)wp[W][5] - (float)wq[W][5];                    \
        float d6 = (float)wp[W][6] - (float)wq[W][6];                    \
        float d7 = (float)wp[W][7] - (float)wq[W][7];                    \
        union { bf16x8 v; unsigned u[4]; } a;                            \
        a.u[0] = cvt_pk_bf16(d0 * d0, d1 * d1);                          \
        a.u[1] = cvt_pk_bf16(d2 * d2, d3 * d3);                          \
        a.u[2] = cvt_pk_bf16(d4 * d4, d5 * d5);                          \
        a.u[3] = cvt_pk_bf16(d6 * d6, d7 * d7);                          \
        *(bf16x8*)(&Abuf[BUF][0] + r * 64 + wslot) = a.v;                \
    }

#define MFMA_STEP(S, BUF)                                                \
    {                                                                    \
        const short* ab = &Abuf[BUF][0];                                 \
        __builtin_amdgcn_s_setprio(1);                                   \
        _Pragma("unroll")                                                \
        for (int kk = 0; kk < 2; ++kk) {                                 \
            int bs = ((S) * 8 + kk * 4 + g) ^ (c & 7);                   \
            bf16x8 bf0 = *(const bf16x8*)(Blds + ((cg * 32 + c) * 32 + bs) * 8);      \
            bf16x8 bf1 = *(const bf16x8*)(Blds + ((cg * 32 + 16 + c) * 32 + bs) * 8); \
            _Pragma("unroll")                                            \
            for (int m = 0; m < 4; ++m) {                                \
                int row = rh * 64 + m * 16 + c;                          \
                bf16x8 af = *(const bf16x8*)(ab + row * 64 +             \
                                             (((kk * 4 + g) ^ (c & 7)) * 8)); \
                acc[m][0] = __builtin_amdgcn_mfma_f32_16x16x32_bf16(     \
                    bf0, af, acc[m][0], 0, 0, 0);                        \
                acc[m][1] = __builtin_amdgcn_mfma_f32_16x16x32_bf16(     \
                    bf1, af, acc[m][1], 0, 0, 0);                        \
            }                                                            \
        }                                                                \
        __builtin_amdgcn_s_setprio(0);                                   \
    }

    // ---- first-tile prologue: windows w0..w2 ----
    {
        const _Float16* pp = emb + (size_t)pi * 256 + sg * 8;
        const _Float16* qp = emb + (size_t)qi * 256 + sg * 8;
        LD(0, pp, qp, 0)
        LD(1, pp, qp, 1)
        LD(2, pp, qp, 2)
    }

    for (int tile = blockIdx.x; tile < NT; tile += NBLK) {
        const int base = tile * 128;
        const _Float16* pp = emb + (size_t)pi * 256 + sg * 8;
        const _Float16* qp = emb + (size_t)qi * 256 + sg * 8;

        // prefetch next tile's indices
        int pi_n = pi, qi_n = qi;
        {
            int t2 = tile + NBLK;
            if (t2 < NT) {
                int im2 = t2 * 128 + r; im2 = im2 < M ? im2 : M - 1;
                pi_n = pidx[im2]; qi_n = qidx[im2];
            }
        }

        CONV(0, 0)

        f32x4 acc[4][2];
#pragma unroll
        for (int m = 0; m < 4; ++m) { acc[m][0] = (f32x4)0.0f; acc[m][1] = (f32x4)0.0f; }

        // s = 0
        __syncthreads();
        LD(3, pp, qp, 3)
        MFMA_STEP(0, 0)
        CONV(1, 1)

        const _Float16* pp_n = emb + (size_t)pi_n * 256 + sg * 8;
        const _Float16* qp_n = emb + (size_t)qi_n * 256 + sg * 8;

        // s = 1
        __syncthreads();
        LD(0, pp_n, qp_n, 0)
        MFMA_STEP(1, 1)
        CONV(2, 0)
        // s = 2
        __syncthreads();
        LD(1, pp_n, qp_n, 1)
        MFMA_STEP(2, 0)
        CONV(3, 1)
        // s = 3
        __syncthreads();
        LD(2, pp_n, qp_n, 2)
        MFMA_STEP(3, 1)

        // ---- epilogue ----
        float part[4];
#pragma unroll
        for (int m = 0; m < 4; ++m) {
            float s = 0.f;
#pragma unroll
            for (int n = 0; n < 2; ++n)
#pragma unroll
                for (int j = 0; j < 4; ++j) {
                    float h = acc[m][n][j] + b1v[n][j];
                    h = h > 0.f ? h : 0.f;
                    s += h * w2v[n][j];
                }
            part[m] = s;
        }
#pragma unroll
        for (int m = 0; m < 4; ++m) {
            part[m] += __shfl_xor(part[m], 16, 64);
            part[m] += __shfl_xor(part[m], 32, 64);
        }

        __syncthreads();            // buf1 MFMA reads done (Red aliases it)
        if (g == 0) {
#pragma unroll
            for (int m = 0; m < 4; ++m)
                Red[cg * 128 + rh * 64 + m * 16 + c] = part[m];
        }
        __syncthreads();
        if (tid < 128) {
            int row = base + tid;
            if (row < M) {
                float s = b2v;
#pragma unroll
                for (int k = 0; k < 8; ++k) s += Red[k * 128 + tid];
                out[row] = s;
            }
        }
        pi = pi_n; qi = qi_n;
        // next tile: CONV(0->buf0) is safe (buf0 last read at MFMA(2));
        // its s=0 barrier orders Red reads before CONV(1->buf1).
    }
#undef LD
#undef CONV
#undef MFMA_STEP
}

// ---------------- f32 fallback (round-6 verbatim structure) ----------------
__global__ __launch_bounds__(1024)
void pair_mlp_f32(const int* __restrict__ pidx, const int* __restrict__ qidx,
                  const float* __restrict__ emb, const short* __restrict__ w1t,
                  const float* __restrict__ b1, const float* __restrict__ w2,
                  const float* __restrict__ b2p, float* __restrict__ out,
                  int M, int NT)
{
    __shared__ short Blds[256 * 256];
    __shared__ short Abuf[2][128 * 64];
    float* Red = (float*)&Abuf[1][0];

    const int tid  = threadIdx.x;
    const int lane = tid & 63;
    const int wv   = tid >> 6;
    const int c    = lane & 15;
    const int g    = lane >> 4;
    const int cg   = wv & 7;
    const int rh   = wv >> 3;

#pragma unroll
    for (int it = 0; it < 8; ++it) {
        int G = it * 1024 + tid;
        int col = G >> 5, kg = G & 31;
        bf16x8 v = *(const bf16x8*)(w1t + G * 8);
        *(bf16x8*)(Blds + (col * 32 + (kg ^ (col & 7))) * 8) = v;
    }

    float b1v[2][4], w2v[2][4];
#pragma unroll
    for (int n = 0; n < 2; ++n)
#pragma unroll
        for (int j = 0; j < 4; ++j) {
            b1v[n][j] = b1[cg * 32 + n * 16 + g * 4 + j];
            w2v[n][j] = w2[cg * 32 + n * 16 + g * 4 + j];
        }
    const float b2v = b2p[0];
    __syncthreads();

    const int r  = tid >> 3;
    const int sg = tid & 7;
    const int wslot = (sg ^ (r & 7)) * 8;

    int im0 = blockIdx.x * 128 + r; im0 = im0 < M ? im0 : M - 1;
    int pi = pidx[im0], qi = qidx[im0];

#define LOADW(W, S)                                                      \
    {                                                                    \
        const float* ps = pp + (S) * 64;                                 \
        const float* qs = qp + (S) * 64;                                 \
        P0_##W = ((const float4*)ps)[0]; P1_##W = ((const float4*)ps)[1];\
        Q0_##W = ((const float4*)qs)[0]; Q1_##W = ((const float4*)qs)[1];\
    }

#define CONVF(W, BUF)                                                    \
    {                                                                    \
        float d0 = P0_##W.x - Q0_##W.x, d1 = P0_##W.y - Q0_##W.y;        \
        float d2 = P0_##W.z - Q0_##W.z, d3 = P0_##W.w - Q0_##W.w;        \
        float d4 = P1_##W.x - Q1_##W.x, d5 = P1_##W.y - Q1_##W.y;        \
        float d6 = P1_##W.z - Q1_##W.z, d7 = P1_##W.w - Q1_##W.w;        \
        union { bf16x8 v; unsigned u[4]; } a;                            \
        a.u[0] = cvt_pk_bf16(d0 * d0, d1 * d1);                          \
        a.u[1] = cvt_pk_bf16(d2 * d2, d3 * d3);                          \
        a.u[2] = cvt_pk_bf16(d4 * d4, d5 * d5);                          \
        a.u[3] = cvt_pk_bf16(d6 * d6, d7 * d7);                          \
        *(bf16x8*)(&Abuf[BUF][0] + r * 64 + wslot) = a.v;                \
    }

#define MFMA_STEPF(S, BUF)                                               \
    {                                                                    \
        const short* ab = &Abuf[BUF][0];                                 \
        _Pragma("unroll")                                                \
        for (int kk = 0; kk < 2; ++kk) {                                 \
            int bs = ((S) * 8 + kk * 4 + g) ^ (c & 7);                   \
            bf16x8 bf0 = *(const bf16x8*)(Blds + ((cg * 32 + c) * 32 + bs) * 8);      \
            bf16x8 bf1 = *(const bf16x8*)(Blds + ((cg * 32 + 16 + c) * 32 + bs) * 8); \
            _Pragma("unroll")                                            \
            for (int m = 0; m < 4; ++m) {                                \
                int row = rh * 64 + m * 16 + c;                          \
                bf16x8 af = *(const bf16x8*)(ab + row * 64 +             \
                                             (((kk * 4 + g) ^ (c & 7)) * 8)); \
                acc[m][0] = __builtin_amdgcn_mfma_f32_16x16x32_bf16(     \
                    bf0, af, acc[m][0], 0, 0, 0);                        \
                acc[m][1] = __builtin_amdgcn_mfma_f32_16x16x32_bf16(     \
                    bf1, af, acc[m][1], 0, 0, 0);                        \
            }                                                            \
        }                                                                \
    }

    for (int tile = blockIdx.x; tile < NT; tile += NBLK) {
        const int base = tile * 128;
        const float* pp = emb + (size_t)pi * 256 + sg * 8;
        const float* qp = emb + (size_t)qi * 256 + sg * 8;

        float4 P0_0, P1_0, Q0_0, Q1_0, P0_1, P1_1, Q0_1, Q1_1;
        LOADW(0, 0)
        LOADW(1, 1)

        int pi_n = pi, qi_n = qi;
        {
            int t2 = tile + NBLK;
            if (t2 < NT) {
                int im2 = t2 * 128 + r; im2 = im2 < M ? im2 : M - 1;
                pi_n = pidx[im2]; qi_n = qidx[im2];
            }
        }

        CONVF(0, 0)

        f32x4 acc[4][2];
#pragma unroll
        for (int m = 0; m < 4; ++m) { acc[m][0] = (f32x4)0.0f; acc[m][1] = (f32x4)0.0f; }

        __syncthreads();
        LOADW(0, 2)
        MFMA_STEPF(0, 0)
        CONVF(1, 1)
        __syncthreads();
        LOADW(1, 3)
        MFMA_STEPF(1, 1)
        CONVF(0, 0)
        __syncthreads();
        MFMA_STEPF(2, 0)
        CONVF(1, 1)
        __syncthreads();
        MFMA_STEPF(3, 1)

        float part[4];
#pragma unroll
        for (int m = 0; m < 4; ++m) {
            float s = 0.f;
#pragma unroll
            for (int n = 0; n < 2; ++n)
#pragma unroll
                for (int j = 0; j < 4; ++j) {
                    float h = acc[m][n][j] + b1v[n][j];
                    h = h > 0.f ? h : 0.f;
                    s += h * w2v[n][j];
                }
            part[m] = s;
        }
#pragma unroll
        for (int m = 0; m < 4; ++m) {
            part[m] += __shfl_xor(part[m], 16, 64);
            part[m] += __shfl_xor(part[m], 32, 64);
        }

        __syncthreads();
        if (g == 0) {
#pragma unroll
            for (int m = 0; m < 4; ++m)
                Red[cg * 128 + rh * 64 + m * 16 + c] = part[m];
        }
        __syncthreads();
        if (tid < 128) {
            int row = base + tid;
            if (row < M) {
                float s = b2v;
#pragma unroll
                for (int k = 0; k < 8; ++k) s += Red[k * 128 + tid];
                out[row] = s;
            }
        }
        pi = pi_n; qi = qi_n;
    }
#undef LOADW
#undef CONVF
#undef MFMA_STEPF
}

extern "C" void kernel_launch(void* const* d_in, const int* in_sizes, int n_in,
                              void* d_out, int out_size, void* d_ws, size_t ws_size,
                              hipStream_t stream) {
    const int*   p   = (const int*)d_in[0];
    const int*   q   = (const int*)d_in[1];
    const float* emb = (const float*)d_in[2];
    const float* W1  = (const float*)d_in[3];
    const float* b1  = (const float*)d_in[4];
    const float* W2  = (const float*)d_in[5];
    const float* b2  = (const float*)d_in[6];
    float* out = (float*)d_out;
    int M = in_sizes[0];
    int embElems = in_sizes[2];            // 100000 * 256
    int NT = (M + 127) / 128;

    short* w1t = (short*)d_ws;             // 128 KB at offset 0
    size_t embOff = 131072;
    size_t need = embOff + (size_t)embElems * 2;

    prep_w1t<<<256, 256, 0, stream>>>(W1, w1t);

    if (ws_size >= need) {
        _Float16* emb16 = (_Float16*)((char*)d_ws + embOff);
        int n8 = embElems / 8;
        prep_emb16<<<(n8 + 255) / 256, 256, 0, stream>>>(emb, emb16, n8);
        pair_mlp_f16<<<NBLK, 1024, 0, stream>>>(p, q, emb16, w1t, b1, W2, b2,
                                                out, M, NT);
    } else {
        pair_mlp_f32<<<NBLK, 1024, 0, stream>>>(p, q, emb, w1t, b1, W2, b2,
                                                out, M, NT);
    }
}

// Round 9
// 108.932 us; speedup vs baseline: 3.7199x; 1.0228x over previous
//
#include <hip/hip_runtime.h>
#include <hip/hip_bf16.h>

typedef __attribute__((ext_vector_type(8))) short s16x8;
typedef __attribute__((ext_vector_type(4))) float f32x4;
typedef _Float16 h16x8 __attribute__((ext_vector_type(8)));
typedef __fp16 fp16x2 __attribute__((ext_vector_type(2)));

// W1 [K=256][N=256] fp32 -> W1T [N=256][K=256] f16
__global__ void prep_w1t(const float* __restrict__ W1, short* __restrict__ W1T) {
    int t = blockIdx.x * 256 + threadIdx.x;
    int n = t >> 8, k = t & 255;
    union { _Float16 h; short s; } u;
    u.h = (_Float16)W1[k * 256 + n];
    W1T[t] = u.s;
}

// embedding f32 -> f16 (halves gather bytes)
__global__ void prep_emb16(const float* __restrict__ src, _Float16* __restrict__ dst,
                           int n8) {
    int t = blockIdx.x * 256 + threadIdx.x;
    if (t >= n8) return;
    const float4 a = ((const float4*)src)[t * 2];
    const float4 b = ((const float4*)src)[t * 2 + 1];
    h16x8 h;
    h[0] = (_Float16)a.x; h[1] = (_Float16)a.y;
    h[2] = (_Float16)a.z; h[3] = (_Float16)a.w;
    h[4] = (_Float16)b.x; h[5] = (_Float16)b.y;
    h[6] = (_Float16)b.z; h[7] = (_Float16)b.w;
    *(h16x8*)(dst + t * 8) = h;
}

#define NBLK 256

// Persistent kernel: 256 blocks x 1024 threads (16 waves, 4/SIMD).
// LDS: full W1T f16 (128 KB, XOR-swizzled) + double-buffered A K=64 slices
// (2 x 16 KB f16) = 160 KiB; epilogue Red aliases Abuf[1].
// Packed-f16 conv (v_pk_sub/v_pk_mul, no f32 round-trip); f16 MFMA;
// b1 folded into accumulator init; 4 rotating cross-tile load windows.
__global__ __launch_bounds__(1024)
void pair_mlp_f16(const int* __restrict__ pidx, const int* __restrict__ qidx,
                  const _Float16* __restrict__ emb, const short* __restrict__ w1t,
                  const float* __restrict__ b1, const float* __restrict__ w2,
                  const float* __restrict__ b2p, float* __restrict__ out,
                  int M, int NT)
{
    __shared__ short Blds[256 * 256];     // 128 KB: [col][kgran ^ (col&7)]
    __shared__ short Abuf[2][128 * 64];   // 2 x 16 KB K-slices (f16 bits)
    float* Red = (float*)&Abuf[1][0];     // 4 KB, aliased (dead at epilogue)

    const int tid  = threadIdx.x;
    const int lane = tid & 63;
    const int wv   = tid >> 6;     // 0..15
    const int c    = lane & 15;
    const int g    = lane >> 4;
    const int cg   = wv & 7;       // col-group (32 cols)
    const int rh   = wv >> 3;      // row-half (64 rows)

    // ---- stage W1T -> LDS once ----
#pragma unroll
    for (int it = 0; it < 8; ++it) {
        int G = it * 1024 + tid;
        int col = G >> 5, kg = G & 31;
        s16x8 v = *(const s16x8*)(w1t + G * 8);
        *(s16x8*)(Blds + (col * 32 + (kg ^ (col & 7))) * 8) = v;
    }

    // epilogue constants: cols cg*32 + n*16 + g*4 + j
    f32x4 b1q[2];
    float w2v[2][4];
#pragma unroll
    for (int n = 0; n < 2; ++n)
#pragma unroll
        for (int j = 0; j < 4; ++j) {
            b1q[n][j]  = b1[cg * 32 + n * 16 + g * 4 + j];
            w2v[n][j]  = w2[cg * 32 + n * 16 + g * 4 + j];
        }
    const float b2v = b2p[0];
    __syncthreads();

    const int r  = tid >> 3;       // gather row 0..127
    const int sg = tid & 7;        // 8-elem K-granule within 64-K slice
    const int wslot = (sg ^ (r & 7)) * 8;

    int im0 = blockIdx.x * 128 + r; im0 = im0 < M ? im0 : M - 1;
    int pi = pidx[im0], qi = qidx[im0];

    h16x8 wp[4], wq[4];            // 4 rotating windows

#define LD(W, PP, QP, S)                                                 \
    {                                                                    \
        wp[W] = *(const h16x8*)((PP) + (S) * 64);                        \
        wq[W] = *(const h16x8*)((QP) + (S) * 64);                        \
    }

// packed f16: d = p - q; s = d*d  (v_pk_sub_f16 x4, v_pk_mul_f16 x4)
#define CONV(W, BUF)                                                     \
    {                                                                    \
        h16x8 d = wp[W] - wq[W];                                         \
        h16x8 s = d * d;                                                 \
        *(h16x8*)(&Abuf[BUF][0] + r * 64 + wslot) = s;                   \
    }

#define MFMA_STEP(S, BUF)                                                \
    {                                                                    \
        const short* ab = &Abuf[BUF][0];                                 \
        __builtin_amdgcn_s_setprio(1);                                   \
        _Pragma("unroll")                                                \
        for (int kk = 0; kk < 2; ++kk) {                                 \
            int bs = ((S) * 8 + kk * 4 + g) ^ (c & 7);                   \
            h16x8 bf0 = *(const h16x8*)(Blds + ((cg * 32 + c) * 32 + bs) * 8);      \
            h16x8 bf1 = *(const h16x8*)(Blds + ((cg * 32 + 16 + c) * 32 + bs) * 8); \
            _Pragma("unroll")                                            \
            for (int m = 0; m < 4; ++m) {                                \
                int row = rh * 64 + m * 16 + c;                          \
                h16x8 af = *(const h16x8*)(ab + row * 64 +               \
                                           (((kk * 4 + g) ^ (c & 7)) * 8)); \
                acc[m][0] = __builtin_amdgcn_mfma_f32_16x16x32_f16(      \
                    bf0, af, acc[m][0], 0, 0, 0);                        \
                acc[m][1] = __builtin_amdgcn_mfma_f32_16x16x32_f16(      \
                    bf1, af, acc[m][1], 0, 0, 0);                        \
            }                                                            \
        }                                                                \
        __builtin_amdgcn_s_setprio(0);                                   \
    }

    // ---- first-tile prologue: windows w0..w2 ----
    {
        const _Float16* pp = emb + (size_t)pi * 256 + sg * 8;
        const _Float16* qp = emb + (size_t)qi * 256 + sg * 8;
        LD(0, pp, qp, 0)
        LD(1, pp, qp, 1)
        LD(2, pp, qp, 2)
    }

    for (int tile = blockIdx.x; tile < NT; tile += NBLK) {
        const int base = tile * 128;
        const _Float16* pp = emb + (size_t)pi * 256 + sg * 8;
        const _Float16* qp = emb + (size_t)qi * 256 + sg * 8;

        // prefetch next tile's indices
        int pi_n = pi, qi_n = qi;
        {
            int t2 = tile + NBLK;
            if (t2 < NT) {
                int im2 = t2 * 128 + r; im2 = im2 < M ? im2 : M - 1;
                pi_n = pidx[im2]; qi_n = qidx[im2];
            }
        }

        CONV(0, 0)

        f32x4 acc[4][2];
#pragma unroll
        for (int m = 0; m < 4; ++m) { acc[m][0] = b1q[0]; acc[m][1] = b1q[1]; }

        // s = 0
        __syncthreads();
        LD(3, pp, qp, 3)
        MFMA_STEP(0, 0)
        CONV(1, 1)

        const _Float16* pp_n = emb + (size_t)pi_n * 256 + sg * 8;
        const _Float16* qp_n = emb + (size_t)qi_n * 256 + sg * 8;

        // s = 1
        __syncthreads();
        LD(0, pp_n, qp_n, 0)
        MFMA_STEP(1, 1)
        CONV(2, 0)
        // s = 2
        __syncthreads();
        LD(1, pp_n, qp_n, 1)
        MFMA_STEP(2, 0)
        CONV(3, 1)
        // s = 3
        __syncthreads();
        LD(2, pp_n, qp_n, 2)
        MFMA_STEP(3, 1)

        // ---- epilogue: h already includes b1; relu-dot, reduce over g ----
        float part[4];
#pragma unroll
        for (int m = 0; m < 4; ++m) {
            float s = 0.f;
#pragma unroll
            for (int n = 0; n < 2; ++n)
#pragma unroll
                for (int j = 0; j < 4; ++j) {
                    float h = acc[m][n][j];
                    h = h > 0.f ? h : 0.f;
                    s += h * w2v[n][j];
                }
            part[m] = s;
        }
#pragma unroll
        for (int m = 0; m < 4; ++m) {
            part[m] += __shfl_xor(part[m], 16, 64);
            part[m] += __shfl_xor(part[m], 32, 64);
        }

        __syncthreads();            // buf1 MFMA reads done (Red aliases it)
        if (g == 0) {
#pragma unroll
            for (int m = 0; m < 4; ++m)
                Red[cg * 128 + rh * 64 + m * 16 + c] = part[m];
        }
        __syncthreads();
        if (tid < 128) {
            int row = base + tid;
            if (row < M) {
                float s = b2v;
#pragma unroll
                for (int k = 0; k < 8; ++k) s += Red[k * 128 + tid];
                out[row] = s;
            }
        }
        pi = pi_n; qi = qi_n;
    }
#undef LD
#undef CONV
#undef MFMA_STEP
}

// ---------------- f32-gather fallback (only if ws too small for emb16) ----
__global__ __launch_bounds__(1024)
void pair_mlp_f32(const int* __restrict__ pidx, const int* __restrict__ qidx,
                  const float* __restrict__ emb, const short* __restrict__ w1t,
                  const float* __restrict__ b1, const float* __restrict__ w2,
                  const float* __restrict__ b2p, float* __restrict__ out,
                  int M, int NT)
{
    __shared__ short Blds[256 * 256];
    __shared__ short Abuf[2][128 * 64];
    float* Red = (float*)&Abuf[1][0];

    const int tid  = threadIdx.x;
    const int lane = tid & 63;
    const int wv   = tid >> 6;
    const int c    = lane & 15;
    const int g    = lane >> 4;
    const int cg   = wv & 7;
    const int rh   = wv >> 3;

#pragma unroll
    for (int it = 0; it < 8; ++it) {
        int G = it * 1024 + tid;
        int col = G >> 5, kg = G & 31;
        s16x8 v = *(const s16x8*)(w1t + G * 8);
        *(s16x8*)(Blds + (col * 32 + (kg ^ (col & 7))) * 8) = v;
    }

    f32x4 b1q[2];
    float w2v[2][4];
#pragma unroll
    for (int n = 0; n < 2; ++n)
#pragma unroll
        for (int j = 0; j < 4; ++j) {
            b1q[n][j] = b1[cg * 32 + n * 16 + g * 4 + j];
            w2v[n][j] = w2[cg * 32 + n * 16 + g * 4 + j];
        }
    const float b2v = b2p[0];
    __syncthreads();

    const int r  = tid >> 3;
    const int sg = tid & 7;
    const int wslot = (sg ^ (r & 7)) * 8;

    int im0 = blockIdx.x * 128 + r; im0 = im0 < M ? im0 : M - 1;
    int pi = pidx[im0], qi = qidx[im0];

#define LOADW(W, S)                                                      \
    {                                                                    \
        const float* ps = pp + (S) * 64;                                 \
        const float* qs = qp + (S) * 64;                                 \
        P0_##W = ((const float4*)ps)[0]; P1_##W = ((const float4*)ps)[1];\
        Q0_##W = ((const float4*)qs)[0]; Q1_##W = ((const float4*)qs)[1];\
    }

#define CONVF(W, BUF)                                                    \
    {                                                                    \
        float d0 = P0_##W.x - Q0_##W.x, d1 = P0_##W.y - Q0_##W.y;        \
        float d2 = P0_##W.z - Q0_##W.z, d3 = P0_##W.w - Q0_##W.w;        \
        float d4 = P1_##W.x - Q1_##W.x, d5 = P1_##W.y - Q1_##W.y;        \
        float d6 = P1_##W.z - Q1_##W.z, d7 = P1_##W.w - Q1_##W.w;        \
        union { h16x8 v; fp16x2 p[4]; } a;                               \
        a.p[0] = __builtin_amdgcn_cvt_pkrtz(d0 * d0, d1 * d1);           \
        a.p[1] = __builtin_amdgcn_cvt_pkrtz(d2 * d2, d3 * d3);           \
        a.p[2] = __builtin_amdgcn_cvt_pkrtz(d4 * d4, d5 * d5);           \
        a.p[3] = __builtin_amdgcn_cvt_pkrtz(d6 * d6, d7 * d7);           \
        *(h16x8*)(&Abuf[BUF][0] + r * 64 + wslot) = a.v;                 \
    }

#define MFMA_STEPF(S, BUF)                                               \
    {                                                                    \
        const short* ab = &Abuf[BUF][0];                                 \
        _Pragma("unroll")                                                \
        for (int kk = 0; kk < 2; ++kk) {                                 \
            int bs = ((S) * 8 + kk * 4 + g) ^ (c & 7);                   \
            h16x8 bf0 = *(const h16x8*)(Blds + ((cg * 32 + c) * 32 + bs) * 8);      \
            h16x8 bf1 = *(const h16x8*)(Blds + ((cg * 32 + 16 + c) * 32 + bs) * 8); \
            _Pragma("unroll")                                            \
            for (int m = 0; m < 4; ++m) {                                \
                int row = rh * 64 + m * 16 + c;                          \
                h16x8 af = *(const h16x8*)(ab + row * 64 +               \
                                           (((kk * 4 + g) ^ (c & 7)) * 8)); \
                acc[m][0] = __builtin_amdgcn_mfma_f32_16x16x32_f16(      \
                    bf0, af, acc[m][0], 0, 0, 0);                        \
                acc[m][1] = __builtin_amdgcn_mfma_f32_16x16x32_f16(      \
                    bf1, af, acc[m][1], 0, 0, 0);                        \
            }                                                            \
        }                                                                \
    }

    for (int tile = blockIdx.x; tile < NT; tile += NBLK) {
        const int base = tile * 128;
        const float* pp = emb + (size_t)pi * 256 + sg * 8;
        const float* qp = emb + (size_t)qi * 256 + sg * 8;

        float4 P0_0, P1_0, Q0_0, Q1_0, P0_1, P1_1, Q0_1, Q1_1;
        LOADW(0, 0)
        LOADW(1, 1)

        int pi_n = pi, qi_n = qi;
        {
            int t2 = tile + NBLK;
            if (t2 < NT) {
                int im2 = t2 * 128 + r; im2 = im2 < M ? im2 : M - 1;
                pi_n = pidx[im2]; qi_n = qidx[im2];
            }
        }

        CONVF(0, 0)

        f32x4 acc[4][2];
#pragma unroll
        for (int m = 0; m < 4; ++m) { acc[m][0] = b1q[0]; acc[m][1] = b1q[1]; }

        __syncthreads();
        LOADW(0, 2)
        MFMA_STEPF(0, 0)
        CONVF(1, 1)
        __syncthreads();
        LOADW(1, 3)
        MFMA_STEPF(1, 1)
        CONVF(0, 0)
        __syncthreads();
        MFMA_STEPF(2, 0)
        CONVF(1, 1)
        __syncthreads();
        MFMA_STEPF(3, 1)

        float part[4];
#pragma unroll
        for (int m = 0; m < 4; ++m) {
            float s = 0.f;
#pragma unroll
            for (int n = 0; n < 2; ++n)
#pragma unroll
                for (int j = 0; j < 4; ++j) {
                    float h = acc[m][n][j];
                    h = h > 0.f ? h : 0.f;
                    s += h * w2v[n][j];
                }
            part[m] = s;
        }
#pragma unroll
        for (int m = 0; m < 4; ++m) {
            part[m] += __shfl_xor(part[m], 16, 64);
            part[m] += __shfl_xor(part[m], 32, 64);
        }

        __syncthreads();
        if (g == 0) {
#pragma unroll
            for (int m = 0; m < 4; ++m)
                Red[cg * 128 + rh * 64 + m * 16 + c] = part[m];
        }
        __syncthreads();
        if (tid < 128) {
            int row = base + tid;
            if (row < M) {
                float s = b2v;
#pragma unroll
                for (int k = 0; k < 8; ++k) s += Red[k * 128 + tid];
                out[row] = s;
            }
        }
        pi = pi_n; qi = qi_n;
    }
#undef LOADW
#undef CONVF
#undef MFMA_STEPF
}

extern "C" void kernel_launch(void* const* d_in, const int* in_sizes, int n_in,
                              void* d_out, int out_size, void* d_ws, size_t ws_size,
                              hipStream_t stream) {
    const int*   p   = (const int*)d_in[0];
    const int*   q   = (const int*)d_in[1];
    const float* emb = (const float*)d_in[2];
    const float* W1  = (const float*)d_in[3];
    const float* b1  = (const float*)d_in[4];
    const float* W2  = (const float*)d_in[5];
    const float* b2  = (const float*)d_in[6];
    float* out = (float*)d_out;
    int M = in_sizes[0];
    int embElems = in_sizes[2];            // 100000 * 256
    int NT = (M + 127) / 128;

    short* w1t = (short*)d_ws;             // 128 KB at offset 0
    size_t embOff = 131072;
    size_t need = embOff + (size_t)embElems * 2;

    prep_w1t<<<256, 256, 0, stream>>>(W1, w1t);

    if (ws_size >= need) {
        _Float16* emb16 = (_Float16*)((char*)d_ws + embOff);
        int n8 = embElems / 8;
        prep_emb16<<<(n8 + 255) / 256, 256, 0, stream>>>(emb, emb16, n8);
        pair_mlp_f16<<<NBLK, 1024, 0, stream>>>(p, q, emb16, w1t, b1, W2, b2,
                                                out, M, NT);
    } else {
        pair_mlp_f32<<<NBLK, 1024, 0, stream>>>(p, q, emb, w1t, b1, W2, b2,
                                                out, M, NT);
    }
}